// Round 6
// baseline (940.979 us; speedup 1.0000x reference)
//
#include <hip/hip_runtime.h>
#include <hip/hip_bf16.h>

typedef unsigned short u16;
typedef __attribute__((ext_vector_type(8))) short short8;
typedef __attribute__((ext_vector_type(4))) float f4;

static __device__ __forceinline__ float b2f(u16 u) {
    union { unsigned int i; float f; } x; x.i = ((unsigned int)u) << 16; return x.f;
}
static __device__ __forceinline__ u16 f2b(float f) {
    union { float f; unsigned int i; } x; x.f = f;
    unsigned int r = x.i + 0x7fffu + ((x.i >> 16) & 1u);
    return (u16)(r >> 16);
}
static __device__ __forceinline__ float wave_reduce_sum(float v) {
    #pragma unroll
    for (int off = 32; off > 0; off >>= 1) v += __shfl_down(v, off, 64);
    return v;
}
// async global->LDS, 16B per lane; lane i lands at ldsbase + i*16
static __device__ __forceinline__ void gl2lds(const void* g, void* l) {
    __builtin_amdgcn_global_load_lds(
        (const __attribute__((address_space(1))) void*)g,
        (__attribute__((address_space(3))) void*)l, 16, 0, 0);
}

// ---------------------------------------------------------------- f32 -> bf16 convert
__global__ __launch_bounds__(256) void conv_f32_bf16(
    const float* __restrict__ src, u16* __restrict__ dst, int n)
{
    int i = (blockIdx.x * 256 + threadIdx.x) * 4;
    if (i >= n) return;
    float4 v = *(const float4*)(src + i);
    union { u16 u[4]; uint2 d; } o;
    o.u[0] = f2b(v.x); o.u[1] = f2b(v.y); o.u[2] = f2b(v.z); o.u[3] = f2b(v.w);
    *(uint2*)(dst + i) = o.d;
}

// ---------------------------------------------------------------- transpose f32 -> bf16
__global__ __launch_bounds__(256) void transpose_k(
    const float* __restrict__ in, u16* __restrict__ out,
    int K, int N, int out_stride, int k_off)
{
    __shared__ float t[32][33];
    int kb = blockIdx.x * 32, nb = blockIdx.y * 32;
    int tx = threadIdx.x, ty = threadIdx.y; // blockDim (32,8)
    #pragma unroll
    for (int i = 0; i < 4; i++)
        t[ty + i * 8][tx] = in[(size_t)(kb + ty + i * 8) * N + nb + tx];
    __syncthreads();
    #pragma unroll
    for (int i = 0; i < 4; i++)
        out[(size_t)(nb + ty + i * 8) * out_stride + k_off + kb + tx] =
            f2b(t[tx][ty + i * 8]);
}

// ---------------------------------------------------------------- small MFMA GEMM (<2,2> use)
template<int MT, int NT>   // block tile = (MT*32) x (NT*32); 4 waves in 2x2
__global__ __launch_bounds__(256) void gemm_mfma(
    const u16* __restrict__ A0, const u16* __restrict__ A1,
    int M, int K0, int K1, int N,
    const u16* __restrict__ Bt,
    const float* __restrict__ bias0, const float* __restrict__ bias1,
    int epi_mode, const float* __restrict__ E, int m_div,
    const float* __restrict__ gate, const float* __restrict__ mi1,
    void* __restrict__ Cout, int out_f32)
{
    constexpr int BM = MT * 32, BN = NT * 32;
    constexpr int STG = (BM + BN) * 32;          // shorts per stage
    constexpr int NPF = MT / 2 + NT / 2;         // DMA loads per stage per wave
    constexpr int STAGE_B = 3 * STG * 2;
    __shared__ __align__(16) char smem[STAGE_B];
    short* stg = (short*)smem;

    int tid  = threadIdx.x;
    int wave = tid >> 6, lane = tid & 63;
    int wm = wave >> 1, wn = wave & 1;
    int lrow = lane & 15, quad = lane >> 4;

    int gx = gridDim.x, gy = gridDim.y;
    int bx = blockIdx.x, by = blockIdx.y;
    if ((gy & 7) == 0) {
        int lin = by * gx + bx;
        int xcd = lin & 7, j = lin >> 3;
        by = xcd * (gy >> 3) + j / gx;
        bx = j % gx;
    }
    int bm0 = by * BM, bn0 = bx * BN;
    int Ktot = K0 + K1;
    int KT = Ktot >> 5;

    int r16 = lane >> 2, cc = lane & 3;
    int sw = (r16 >> 1) & 3;
    int coff = (cc ^ sw) * 8;

    auto stage = [&](int s, int k0) {
        const u16* asrc; int lda;
        if (k0 < K0) { asrc = A0 + k0; lda = K0; }
        else         { asrc = A1 + (k0 - K0); lda = K1; }
        short* As = stg + s * STG;
        short* Bs = As + BM * 32;
        #pragma unroll
        for (int i = 0; i < MT / 2; i++) {
            int ar = wave * (BM / 4) + 16 * i;
            gl2lds(asrc + (size_t)(bm0 + ar + r16) * lda + coff, As + ar * 32);
        }
        #pragma unroll
        for (int i = 0; i < NT / 2; i++) {
            int br = wave * (BN / 4) + 16 * i;
            gl2lds(Bt + (size_t)(bn0 + br + r16) * Ktot + k0 + coff, Bs + br * 32);
        }
    };

    f4 acc[MT][NT];
    #pragma unroll
    for (int i = 0; i < MT; i++)
        #pragma unroll
        for (int j = 0; j < NT; j++)
            acc[i][j] = (f4){0.f, 0.f, 0.f, 0.f};

    stage(0, 0);
    if (KT > 1) stage(1, 32);
    int sb = 0;
    int sw2 = (lrow >> 1) & 3;
    for (int kt = 0; kt < KT; kt++) {
        if (kt + 1 < KT) {
            if constexpr (NPF == 2)
                asm volatile("s_waitcnt vmcnt(2) lgkmcnt(0)\ns_barrier" ::: "memory");
            else
                asm volatile("s_waitcnt vmcnt(0) lgkmcnt(0)\ns_barrier" ::: "memory");
        } else {
            asm volatile("s_waitcnt vmcnt(0) lgkmcnt(0)\ns_barrier" ::: "memory");
        }
        const short* Ab = stg + sb * STG;
        const short* Bb = Ab + BM * 32;
        if (kt + 2 < KT) {
            int s2 = sb + 2; if (s2 >= 3) s2 -= 3;
            stage(s2, (kt + 2) * 32);
        }
        short8 af[MT], bfr[NT];
        #pragma unroll
        for (int mt = 0; mt < MT; mt++)
            af[mt] = *(const short8*)&Ab[(wm * (MT * 16) + mt * 16 + lrow) * 32 + (quad ^ sw2) * 8];
        #pragma unroll
        for (int nt = 0; nt < NT; nt++)
            bfr[nt] = *(const short8*)&Bb[(wn * (NT * 16) + nt * 16 + lrow) * 32 + (quad ^ sw2) * 8];
        #pragma unroll
        for (int mt = 0; mt < MT; mt++)
            #pragma unroll
            for (int nt = 0; nt < NT; nt++)
                acc[mt][nt] = __builtin_amdgcn_mfma_f32_16x16x32_bf16(
                    af[mt], bfr[nt], acc[mt][nt], 0, 0, 0);
        sb = (sb + 1 == 3) ? 0 : sb + 1;
    }

    // direct epilogue (small tiles)
    #pragma unroll
    for (int nt = 0; nt < NT; nt++) {
        int n = bn0 + wn * (NT * 16) + nt * 16 + lrow;
        float bv = 0.f;
        if (bias0) bv += bias0[n];
        if (bias1) bv += bias1[n];
        #pragma unroll
        for (int mt = 0; mt < MT; mt++) {
            #pragma unroll
            for (int r = 0; r < 4; r++) {
                int m = bm0 + wm * (MT * 16) + mt * 16 + quad * 4 + r;
                float v = acc[mt][nt][r] + bv;
                if (epi_mode == 1) {
                    v *= E[(size_t)(m / m_div) * N + n];
                } else if (epi_mode == 2) {
                    float g = gate[m];
                    v = g * mi1[(size_t)m * N + n] + (1.f - g) * v;
                }
                if (out_f32) ((float*)Cout)[(size_t)m * N + n] = v;
                else         ((u16*)Cout)[(size_t)m * N + n] = f2b(v);
            }
        }
    }
}

// ---------------------------------------------------------------- fused read-path
// Per 64-row slab: G1 = (kbf@Wrk + brk)*E1 -> g_tile;  G2 = ([G1|kbf]@Wrik + brik)*E2 -> g_tile;
// G3 = G2@Wrci + brci -> rai.  A and B both load global->registers (double-buffered,
// plain local arrays, compile-time indices only -- NO reference-parameter lambdas, no scratch).
// LDS holds ONLY the 64x512 inter-GEMM tile.  K-loops have NO barriers.
#define LOAD_B8(dst, W, ldk, k0) \
  _Pragma("unroll") for (int nt_ = 0; nt_ < 8; nt_++) { \
    dst[nt_] = *(const short8*)&(W)[(size_t)(wc * 128 + nt_ * 16 + lrow) * (ldk) + (k0) + quad * 8]; \
  }
#define LOAD_A2(dst, k0) \
  _Pragma("unroll") for (int t_ = 0; t_ < 2; t_++) { \
    dst[t_] = *(const short8*)&kbf[(size_t)(bm0 + wr * 32 + t_ * 16 + lrow) * 512 + (k0) + quad * 8]; \
  }
#define LOAD_AG(dst, kc0) \
  _Pragma("unroll") for (int t_ = 0; t_ < 2; t_++) { \
    int R_ = wr * 32 + t_ * 16 + lrow; \
    dst[t_] = *(const short8*)&g_tile[R_ * 512 + ((((kc0) + quad) ^ (R_ & 7)) << 3)]; \
  }
#define MFMA16(afr, bfr) \
  _Pragma("unroll") for (int t_ = 0; t_ < 2; t_++) \
    _Pragma("unroll") for (int nt_ = 0; nt_ < 8; nt_++) \
      acc[t_][nt_] = __builtin_amdgcn_mfma_f32_16x16x32_bf16(afr[t_], bfr[nt_], acc[t_][nt_], 0, 0, 0);

__global__ __launch_bounds__(512, 2) void fused_read(
    const u16* __restrict__ kbf, int M,
    const u16* __restrict__ Wrk,  const float* __restrict__ brk,  const float* __restrict__ E1,
    const u16* __restrict__ Wrik, const float* __restrict__ brik, const float* __restrict__ E2,
    const u16* __restrict__ Wrci, const float* __restrict__ brci,
    u16* __restrict__ rai)
{
    __shared__ __align__(16) short g_tile[32768];     // [64][512], 16B-chunk XOR swizzle

    int tid = threadIdx.x, wave = tid >> 6, lane = tid & 63;
    int wr = wave >> 2, wc = wave & 3;                // 2 x 4 wave grid
    int lrow = lane & 15, quad = lane >> 4;

    int bid = blockIdx.x;
    { int nb = gridDim.x; if ((nb & 7) == 0) { int x = bid & 7, j = bid >> 3; bid = x * (nb >> 3) + j; } }
    int bm0 = bid * 64;

    f4 acc[2][8];
    auto clr = [&]() {
        #pragma unroll
        for (int t = 0; t < 2; t++)
            #pragma unroll
            for (int nt = 0; nt < 8; nt++)
                acc[t][nt] = (f4){0.f, 0.f, 0.f, 0.f};
    };

    // accum -> (acc+bias)*E -> bf16 -> g_tile (swizzled chunks)
    int bt0 = bm0 / 196, bt1 = (bm0 + 63) / 196;
    int rsw = (bt1 != bt0) ? (bt1 * 196 - bm0) : 64;
    auto epi_to_gtile = [&](const float* bias, const float* E) {
        #pragma unroll
        for (int nt = 0; nt < 8; nt++) {
            int n = wc * 128 + nt * 16 + lrow;
            float bv = bias[n];
            float e0 = E[(size_t)bt0 * 512 + n];
            float e1 = E[(size_t)bt1 * 512 + n];
            #pragma unroll
            for (int t = 0; t < 2; t++)
                #pragma unroll
                for (int r = 0; r < 4; r++) {
                    int row = wr * 32 + t * 16 + quad * 4 + r;
                    float e = (row < rsw) ? e0 : e1;
                    u16 h = f2b((acc[t][nt][r] + bv) * e);
                    int chunk = (n >> 3) ^ (row & 7);
                    g_tile[row * 512 + chunk * 8 + (n & 7)] = (short)h;
                }
        }
    };

    short8 a0[2], a1[2], b0[8], b1[8];

    // ================= G1: kbf @ Wrk ================= (no barriers)
    clr();
    LOAD_A2(a0, 0) LOAD_B8(b0, Wrk, 512, 0)
    for (int kt = 0; kt < 16; kt += 2) {
        LOAD_A2(a1, (kt + 1) * 32) LOAD_B8(b1, Wrk, 512, (kt + 1) * 32)
        MFMA16(a0, b0)
        if (kt + 2 < 16) { LOAD_A2(a0, (kt + 2) * 32) LOAD_B8(b0, Wrk, 512, (kt + 2) * 32) }
        MFMA16(a1, b1)
    }
    epi_to_gtile(brk, E1);
    __syncthreads();

    // ================= G2a: g_tile(=G1) @ Wrik[k<512] ================= (no barriers)
    clr();
    LOAD_AG(a0, 0) LOAD_B8(b0, Wrik, 1024, 0)
    for (int kt = 0; kt < 16; kt += 2) {
        LOAD_AG(a1, (kt + 1) * 4) LOAD_B8(b1, Wrik, 1024, (kt + 1) * 32)
        MFMA16(a0, b0)
        if (kt + 2 < 16) { LOAD_AG(a0, (kt + 2) * 4) LOAD_B8(b0, Wrik, 1024, (kt + 2) * 32) }
        MFMA16(a1, b1)
    }
    // ================= G2b: kbf @ Wrik[k>=512] ================= (acc continues)
    LOAD_A2(a0, 0) LOAD_B8(b0, Wrik, 1024, 512)
    for (int kt = 0; kt < 16; kt += 2) {
        LOAD_A2(a1, (kt + 1) * 32) LOAD_B8(b1, Wrik, 1024, 512 + (kt + 1) * 32)
        MFMA16(a0, b0)
        if (kt + 2 < 16) { LOAD_A2(a0, (kt + 2) * 32) LOAD_B8(b0, Wrik, 1024, 512 + (kt + 2) * 32) }
        MFMA16(a1, b1)
    }
    __syncthreads();              // all G2a g_tile reads done before overwrite
    epi_to_gtile(brik, E2);
    __syncthreads();

    // ================= G3: g_tile(=G2) @ Wrci ================= (no barriers)
    clr();
    LOAD_AG(a0, 0) LOAD_B8(b0, Wrci, 512, 0)
    for (int kt = 0; kt < 16; kt += 2) {
        LOAD_AG(a1, (kt + 1) * 4) LOAD_B8(b1, Wrci, 512, (kt + 1) * 32)
        MFMA16(a0, b0)
        if (kt + 2 < 16) { LOAD_AG(a0, (kt + 2) * 4) LOAD_B8(b0, Wrci, 512, (kt + 2) * 32) }
        MFMA16(a1, b1)
    }
    __syncthreads();              // all G3 g_tile reads done before overwrite
    // final epilogue: +brci, linear bf16 into g_tile, then coalesced copy out
    #pragma unroll
    for (int nt = 0; nt < 8; nt++) {
        int n = wc * 128 + nt * 16 + lrow;
        float bv = brci[n];
        #pragma unroll
        for (int t = 0; t < 2; t++)
            #pragma unroll
            for (int r = 0; r < 4; r++) {
                int row = wr * 32 + t * 16 + quad * 4 + r;
                g_tile[row * 512 + n] = (short)f2b(acc[t][nt][r] + bv);
            }
    }
    __syncthreads();
    #pragma unroll
    for (int p = 0; p < 8; p++) {
        int idx = p * 512 + tid;                 // 16B units, 4096 total
        short8 v = *(const short8*)&g_tile[idx * 8];
        *(short8*)&rai[(size_t)bm0 * 512 + (size_t)idx * 8] = v;
    }
}
#undef LOAD_B8
#undef LOAD_A2
#undef LOAD_AG
#undef MFMA16

// ---------------------------------------------------------------- control attention
__global__ __launch_bounds__(256) void control_attn(
    const float* __restrict__ cqi, const float* __restrict__ cws,
    const float* __restrict__ Wcai, const float* __restrict__ bcai,
    float* __restrict__ ci_f32, float* __restrict__ ci_out)
{
    int b = blockIdx.x, tid = threadIdx.x;
    __shared__ float tW[512];
    __shared__ float p[128];
    __shared__ float inv_l;
    for (int d = tid; d < 512; d += 256)
        tW[d] = cqi[(size_t)b * 512 + d] * Wcai[d];
    __syncthreads();
    int wave = tid >> 6, lane = tid & 63;
    const float* cwsb = cws + (size_t)b * 128 * 512;
    for (int s = wave; s < 128; s += 4) {
        const float* row = cwsb + (size_t)s * 512 + lane * 8;
        float acc = 0.f;
        #pragma unroll
        for (int j = 0; j < 8; j++) acc += tW[lane * 8 + j] * row[j];
        acc = wave_reduce_sum(acc);
        if (lane == 0) p[s] = acc + bcai[0];
    }
    __syncthreads();
    if (tid == 0) {
        float m = -1e30f;
        for (int s = 0; s < 128; s++) m = fmaxf(m, p[s]);
        float l = 0.f;
        for (int s = 0; s < 128; s++) { float e = __expf(p[s] - m); p[s] = e; l += e; }
        inv_l = 1.f / l;
    }
    __syncthreads();
    float inv = inv_l;
    for (int d = tid; d < 512; d += 256) {
        float acc = 0.f;
        for (int s = 0; s < 128; s++) acc += p[s] * cwsb[(size_t)s * 512 + d];
        acc *= inv;
        ci_f32[(size_t)b * 512 + d] = acc;
        ci_out[(size_t)b * 512 + d] = acc;
    }
}

// ---------------------------------------------------------------- read reduce
__global__ __launch_bounds__(256) void read_reduce(
    const u16* __restrict__ rai, const u16* __restrict__ Kb, u16* __restrict__ ri)
{
    int b = blockIdx.x >> 1;
    int d = ((blockIdx.x & 1) << 8) + threadIdx.x;
    const u16* rb = rai + (size_t)b * 196 * 512 + d;
    const u16* kb = Kb + (size_t)b * 196 * 512 + d;
    float m1[14], il1[14];
    #pragma unroll
    for (int w = 0; w < 14; w++) {
        float m = -1e30f, s = 0.f;
        #pragma unroll
        for (int h = 0; h < 14; h++) {
            float v = b2f(rb[(size_t)(h * 14 + w) * 512]);
            float nm = fmaxf(m, v);
            s = s * __expf(m - nm) + __expf(v - nm);
            m = nm;
        }
        m1[w] = m; il1[w] = 1.f / s;
    }
    float acc = 0.f;
    #pragma unroll
    for (int h = 0; h < 14; h++) {
        float pv[14], ss = 0.f;
        #pragma unroll
        for (int w = 0; w < 14; w++) {
            float pr = __expf(b2f(rb[(size_t)(h * 14 + w) * 512]) - m1[w]) * il1[w];
            float e = __expf(pr);
            pv[w] = e; ss += e;
        }
        float il2 = 1.f / ss;
        #pragma unroll
        for (int w = 0; w < 14; w++)
            acc += pv[w] * il2 * b2f(kb[(size_t)(h * 14 + w) * 512]);
    }
    ri[(size_t)b * 512 + d] = f2b(acc);
}

// ---------------------------------------------------------------- write attention + gate
__global__ __launch_bounds__(256) void write_attn(
    const float* __restrict__ ci_f32, const float* __restrict__ C_past,
    const float* __restrict__ M_past,
    const float* __restrict__ Wwcc, const float* __restrict__ bwcc,
    const float* __restrict__ Wwci, const float* __restrict__ bwci,
    u16* __restrict__ mi_sa, float* __restrict__ gate)
{
    int b = blockIdx.x, tid = threadIdx.x;
    __shared__ float c[512];
    __shared__ float pt[12];
    __shared__ float red[256];
    for (int d = tid; d < 512; d += 256) c[d] = ci_f32[(size_t)b * 512 + d];
    __syncthreads();
    float g = 0.f;
    for (int d = tid; d < 512; d += 256) g += c[d] * Wwci[d];
    red[tid] = g;
    __syncthreads();
    for (int s = 128; s > 0; s >>= 1) {
        if (tid < s) red[tid] += red[tid + s];
        __syncthreads();
    }
    int wave = tid >> 6, lane = tid & 63;
    const float* cp = C_past + (size_t)b * 12 * 512;
    for (int t = wave; t < 12; t += 4) {
        float acc = 0.f;
        #pragma unroll
        for (int j = 0; j < 8; j++) {
            int d = lane * 8 + j;
            acc += c[d] * Wwcc[d] * cp[(size_t)t * 512 + d];
        }
        acc = wave_reduce_sum(acc);
        if (lane == 0) pt[t] = acc + bwcc[0];
    }
    __syncthreads();
    if (tid == 0) {
        float m = -1e30f;
        for (int t = 0; t < 12; t++) m = fmaxf(m, pt[t]);
        float l = 0.f;
        for (int t = 0; t < 12; t++) { float e = __expf(pt[t] - m); pt[t] = e; l += e; }
        float invl = 1.f / l;
        for (int t = 0; t < 12; t++) pt[t] *= invl;
        gate[b] = 1.f / (1.f + __expf(-(red[0] + bwci[0])));
    }
    __syncthreads();
    const float* mp = M_past + (size_t)b * 12 * 512;
    for (int d = tid; d < 512; d += 256) {
        float acc = 0.f;
        #pragma unroll
        for (int t = 0; t < 12; t++) acc += pt[t] * mp[(size_t)t * 512 + d];
        mi_sa[(size_t)b * 512 + d] = f2b(acc);
    }
}

// ---------------------------------------------------------------- launch
extern "C" void kernel_launch(void* const* d_in, const int* in_sizes, int n_in,
                              void* d_out, int out_size, void* d_ws, size_t ws_size,
                              hipStream_t stream) {
    (void)in_sizes; (void)n_in; (void)out_size;
    const int B = 256, D = 512, HW = 196;

    const float* ci_1   = (const float*)d_in[0];
    const float* mi_1   = (const float*)d_in[1];
    const float* q      = (const float*)d_in[2];
    const float* cws    = (const float*)d_in[3];
    const float* Kin    = (const float*)d_in[4];
    const float* C_past = (const float*)d_in[5];
    const float* M_past = (const float*)d_in[6];
    const float* W_cq   = (const float*)d_in[7];
    const float* b_cq   = (const float*)d_in[8];
    const float* W_cqi  = (const float*)d_in[9];
    const float* b_cqi  = (const float*)d_in[10];
    const float* W_cai  = (const float*)d_in[11];
    const float* b_cai  = (const float*)d_in[12];
    const float* W_rm   = (const float*)d_in[13];
    const float* b_rm   = (const float*)d_in[14];
    const float* W_rk   = (const float*)d_in[15];
    const float* b_rk   = (const float*)d_in[16];
    const float* W_rik  = (const float*)d_in[17];
    const float* b_rik  = (const float*)d_in[18];
    const float* W_rci  = (const float*)d_in[19];
    const float* b_rci  = (const float*)d_in[20];
    const float* W_wrm  = (const float*)d_in[21];
    const float* b_wrm  = (const float*)d_in[22];
    const float* W_wcc  = (const float*)d_in[23];
    const float* b_wcc  = (const float*)d_in[24];
    const float* W_wsa  = (const float*)d_in[25];
    const float* b_wsa  = (const float*)d_in[26];
    const float* W_winfo= (const float*)d_in[27];
    const float* b_winfo= (const float*)d_in[28];
    const float* W_wci  = (const float*)d_in[29];
    const float* b_wci  = (const float*)d_in[30];

    float* out_ci = (float*)d_out;
    float* out_mi = (float*)d_out + (size_t)B * D;

    char* ws = (char*)d_ws;
    size_t off = 0;
    auto alloc = [&](size_t bytes) -> void* {
        void* p = ws + off; off += (bytes + 255) & ~(size_t)255; return p;
    };
    u16* wt_cq    = (u16*)alloc((size_t)D * D * 2);
    u16* wt_cqi   = (u16*)alloc((size_t)D * 2 * D * 2);
    u16* wt_rm    = (u16*)alloc((size_t)D * D * 2);
    u16* wt_rk    = (u16*)alloc((size_t)D * D * 2);
    u16* wt_rik   = (u16*)alloc((size_t)D * 2 * D * 2);
    u16* wt_rci   = (u16*)alloc((size_t)D * D * 2);
    u16* wt_wrm   = (u16*)alloc((size_t)D * 2 * D * 2);
    u16* wt_wsi   = (u16*)alloc((size_t)D * 2 * D * 2);
    u16* qb       = (u16*)alloc((size_t)B * D * 2);
    u16* cib      = (u16*)alloc((size_t)B * D * 2);
    u16* mib      = (u16*)alloc((size_t)B * D * 2);
    u16* qi_buf   = (u16*)alloc((size_t)B * D * 2);
    float* cqi_f32= (float*)alloc((size_t)B * D * 4);
    float* rm_f32 = (float*)alloc((size_t)B * D * 4);
    float* ci_f32 = (float*)alloc((size_t)B * D * 4);
    u16* ri_buf   = (u16*)alloc((size_t)B * D * 2);
    u16* misa_buf = (u16*)alloc((size_t)B * D * 2);
    u16* minfo_buf= (u16*)alloc((size_t)B * D * 2);
    float* gate_b = (float*)alloc((size_t)B * 4);

    int chunk_b = 256;
    while (chunk_b > 32) {
        size_t need = off + 2 * (((size_t)chunk_b * HW * D * 2 + 255) & ~(size_t)255);
        if (need <= ws_size) break;
        chunk_b >>= 1;
    }
    u16* kbf  = (u16*)alloc((size_t)chunk_b * HW * D * 2);
    u16* big1 = (u16*)alloc((size_t)chunk_b * HW * D * 2);

    dim3 tb(32, 8);
    transpose_k<<<dim3(D / 32, D / 32), tb, 0, stream>>>(W_cq,   wt_cq,  D,     D, D,     0);
    transpose_k<<<dim3(2 * D / 32, D / 32), tb, 0, stream>>>(W_cqi, wt_cqi, 2 * D, D, 2 * D, 0);
    transpose_k<<<dim3(D / 32, D / 32), tb, 0, stream>>>(W_rm,   wt_rm,  D,     D, D,     0);
    transpose_k<<<dim3(D / 32, D / 32), tb, 0, stream>>>(W_rk,   wt_rk,  D,     D, D,     0);
    transpose_k<<<dim3(2 * D / 32, D / 32), tb, 0, stream>>>(W_rik, wt_rik, 2 * D, D, 2 * D, 0);
    transpose_k<<<dim3(D / 32, D / 32), tb, 0, stream>>>(W_rci,  wt_rci, D,     D, D,     0);
    transpose_k<<<dim3(2 * D / 32, D / 32), tb, 0, stream>>>(W_wrm, wt_wrm, 2 * D, D, 2 * D, 0);
    transpose_k<<<dim3(D / 32, D / 32), tb, 0, stream>>>(W_wsa,  wt_wsi, D,     D, 2 * D, 0);
    transpose_k<<<dim3(D / 32, D / 32), tb, 0, stream>>>(W_winfo,wt_wsi, D,     D, 2 * D, D);

    int nbd = B * D;
    conv_f32_bf16<<<nbd / 1024, 256, 0, stream>>>(q, qb, nbd);
    conv_f32_bf16<<<nbd / 1024, 256, 0, stream>>>(ci_1, cib, nbd);
    conv_f32_bf16<<<nbd / 1024, 256, 0, stream>>>(mi_1, mib, nbd);

    dim3 gsmall(D / 64, B / 64); // (8, 4) = 32 blocks

    gemm_mfma<2,2><<<gsmall, 256, 0, stream>>>(qb, nullptr, B, D, 0, D, wt_cq, b_cq, nullptr,
                                               0, nullptr, 1, nullptr, nullptr, qi_buf, 0);
    gemm_mfma<2,2><<<gsmall, 256, 0, stream>>>(cib, qi_buf, B, D, D, D, wt_cqi, b_cqi, nullptr,
                                               0, nullptr, 1, nullptr, nullptr, cqi_f32, 1);
    control_attn<<<B, 256, 0, stream>>>(cqi_f32, cws, W_cai, b_cai, ci_f32, out_ci);
    gemm_mfma<2,2><<<gsmall, 256, 0, stream>>>(mib, nullptr, B, D, 0, D, wt_rm, b_rm, nullptr,
                                               0, nullptr, 1, nullptr, nullptr, rm_f32, 1);

    for (int c = 0; c < B; c += chunk_b) {
        int mrows = chunk_b * HW;
        const float* Kc = Kin + (size_t)c * HW * D;
        conv_f32_bf16<<<(mrows * D) / 1024, 256, 0, stream>>>(Kc, kbf, mrows * D);
        fused_read<<<mrows / 64, 512, 0, stream>>>(
            kbf, mrows,
            wt_rk,  b_rk,  rm_f32 + (size_t)c * D,
            wt_rik, b_rik, ci_f32 + (size_t)c * D,
            wt_rci, b_rci,
            big1);
        read_reduce<<<chunk_b * 2, 256, 0, stream>>>(big1, kbf, ri_buf + (size_t)c * D);
    }

    gemm_mfma<2,2><<<gsmall, 256, 0, stream>>>(ri_buf, mib, B, D, D, D, wt_wrm, b_wrm, nullptr,
                                               0, nullptr, 1, nullptr, nullptr, minfo_buf, 0);
    write_attn<<<B, 256, 0, stream>>>(ci_f32, C_past, M_past, W_wcc, b_wcc, W_wci, b_wci,
                                      misa_buf, gate_b);
    gemm_mfma<2,2><<<gsmall, 256, 0, stream>>>(misa_buf, minfo_buf, B, D, D, D, wt_wsi,
                                               b_wsa, b_winfo, 2, nullptr, 1, gate_b, mi_1,
                                               out_mi, 1);
}

// Round 7
// 600.910 us; speedup vs baseline: 1.5659x; 1.5659x over previous
//
#include <hip/hip_runtime.h>
#include <hip/hip_bf16.h>

typedef unsigned short u16;
typedef __attribute__((ext_vector_type(8))) short short8;
typedef __attribute__((ext_vector_type(4))) float f4;

static __device__ __forceinline__ float b2f(u16 u) {
    union { unsigned int i; float f; } x; x.i = ((unsigned int)u) << 16; return x.f;
}
static __device__ __forceinline__ u16 f2b(float f) {
    union { float f; unsigned int i; } x; x.f = f;
    unsigned int r = x.i + 0x7fffu + ((x.i >> 16) & 1u);
    return (u16)(r >> 16);
}
static __device__ __forceinline__ float wave_reduce_sum(float v) {
    #pragma unroll
    for (int off = 32; off > 0; off >>= 1) v += __shfl_down(v, off, 64);
    return v;
}
// async global->LDS, 16B per lane; lane i lands at ldsbase + i*16
static __device__ __forceinline__ void gl2lds(const void* g, void* l) {
    __builtin_amdgcn_global_load_lds(
        (const __attribute__((address_space(1))) void*)g,
        (__attribute__((address_space(3))) void*)l, 16, 0, 0);
}

// ---------------------------------------------------------------- f32 -> bf16 convert
__global__ __launch_bounds__(256) void conv_f32_bf16(
    const float* __restrict__ src, u16* __restrict__ dst, int n)
{
    int i = (blockIdx.x * 256 + threadIdx.x) * 4;
    if (i >= n) return;
    float4 v = *(const float4*)(src + i);
    union { u16 u[4]; uint2 d; } o;
    o.u[0] = f2b(v.x); o.u[1] = f2b(v.y); o.u[2] = f2b(v.z); o.u[3] = f2b(v.w);
    *(uint2*)(dst + i) = o.d;
}

// ---------------------------------------------------------------- transpose f32 -> bf16
__global__ __launch_bounds__(256) void transpose_k(
    const float* __restrict__ in, u16* __restrict__ out,
    int K, int N, int out_stride, int k_off)
{
    __shared__ float t[32][33];
    int kb = blockIdx.x * 32, nb = blockIdx.y * 32;
    int tx = threadIdx.x, ty = threadIdx.y; // blockDim (32,8)
    #pragma unroll
    for (int i = 0; i < 4; i++)
        t[ty + i * 8][tx] = in[(size_t)(kb + ty + i * 8) * N + nb + tx];
    __syncthreads();
    #pragma unroll
    for (int i = 0; i < 4; i++)
        out[(size_t)(nb + ty + i * 8) * out_stride + k_off + kb + tx] =
            f2b(t[tx][ty + i * 8]);
}

// ---------------------------------------------------------------- small MFMA GEMM (<2,2> use)
template<int MT, int NT>   // block tile = (MT*32) x (NT*32); 4 waves in 2x2
__global__ __launch_bounds__(256) void gemm_mfma(
    const u16* __restrict__ A0, const u16* __restrict__ A1,
    int M, int K0, int K1, int N,
    const u16* __restrict__ Bt,
    const float* __restrict__ bias0, const float* __restrict__ bias1,
    int epi_mode, const float* __restrict__ E, int m_div,
    const float* __restrict__ gate, const float* __restrict__ mi1,
    void* __restrict__ Cout, int out_f32)
{
    constexpr int BM = MT * 32, BN = NT * 32;
    constexpr int STG = (BM + BN) * 32;          // shorts per stage
    constexpr int NPF = MT / 2 + NT / 2;         // DMA loads per stage per wave
    constexpr int STAGE_B = 3 * STG * 2;
    __shared__ __align__(16) char smem[STAGE_B];
    short* stg = (short*)smem;

    int tid  = threadIdx.x;
    int wave = tid >> 6, lane = tid & 63;
    int wm = wave >> 1, wn = wave & 1;
    int lrow = lane & 15, quad = lane >> 4;

    int gx = gridDim.x, gy = gridDim.y;
    int bx = blockIdx.x, by = blockIdx.y;
    if ((gy & 7) == 0) {
        int lin = by * gx + bx;
        int xcd = lin & 7, j = lin >> 3;
        by = xcd * (gy >> 3) + j / gx;
        bx = j % gx;
    }
    int bm0 = by * BM, bn0 = bx * BN;
    int Ktot = K0 + K1;
    int KT = Ktot >> 5;

    int r16 = lane >> 2, cc = lane & 3;
    int sw = (r16 >> 1) & 3;
    int coff = (cc ^ sw) * 8;

    auto stage = [&](int s, int k0) {
        const u16* asrc; int lda;
        if (k0 < K0) { asrc = A0 + k0; lda = K0; }
        else         { asrc = A1 + (k0 - K0); lda = K1; }
        short* As = stg + s * STG;
        short* Bs = As + BM * 32;
        #pragma unroll
        for (int i = 0; i < MT / 2; i++) {
            int ar = wave * (BM / 4) + 16 * i;
            gl2lds(asrc + (size_t)(bm0 + ar + r16) * lda + coff, As + ar * 32);
        }
        #pragma unroll
        for (int i = 0; i < NT / 2; i++) {
            int br = wave * (BN / 4) + 16 * i;
            gl2lds(Bt + (size_t)(bn0 + br + r16) * Ktot + k0 + coff, Bs + br * 32);
        }
    };

    f4 acc[MT][NT];
    #pragma unroll
    for (int i = 0; i < MT; i++)
        #pragma unroll
        for (int j = 0; j < NT; j++)
            acc[i][j] = (f4){0.f, 0.f, 0.f, 0.f};

    stage(0, 0);
    if (KT > 1) stage(1, 32);
    int sb = 0;
    int sw2 = (lrow >> 1) & 3;
    for (int kt = 0; kt < KT; kt++) {
        if (kt + 1 < KT) {
            if constexpr (NPF == 2)
                asm volatile("s_waitcnt vmcnt(2) lgkmcnt(0)\ns_barrier" ::: "memory");
            else
                asm volatile("s_waitcnt vmcnt(0) lgkmcnt(0)\ns_barrier" ::: "memory");
        } else {
            asm volatile("s_waitcnt vmcnt(0) lgkmcnt(0)\ns_barrier" ::: "memory");
        }
        const short* Ab = stg + sb * STG;
        const short* Bb = Ab + BM * 32;
        if (kt + 2 < KT) {
            int s2 = sb + 2; if (s2 >= 3) s2 -= 3;
            stage(s2, (kt + 2) * 32);
        }
        short8 af[MT], bfr[NT];
        #pragma unroll
        for (int mt = 0; mt < MT; mt++)
            af[mt] = *(const short8*)&Ab[(wm * (MT * 16) + mt * 16 + lrow) * 32 + (quad ^ sw2) * 8];
        #pragma unroll
        for (int nt = 0; nt < NT; nt++)
            bfr[nt] = *(const short8*)&Bb[(wn * (NT * 16) + nt * 16 + lrow) * 32 + (quad ^ sw2) * 8];
        #pragma unroll
        for (int mt = 0; mt < MT; mt++)
            #pragma unroll
            for (int nt = 0; nt < NT; nt++)
                acc[mt][nt] = __builtin_amdgcn_mfma_f32_16x16x32_bf16(
                    af[mt], bfr[nt], acc[mt][nt], 0, 0, 0);
        sb = (sb + 1 == 3) ? 0 : sb + 1;
    }

    // direct epilogue (small tiles)
    #pragma unroll
    for (int nt = 0; nt < NT; nt++) {
        int n = bn0 + wn * (NT * 16) + nt * 16 + lrow;
        float bv = 0.f;
        if (bias0) bv += bias0[n];
        if (bias1) bv += bias1[n];
        #pragma unroll
        for (int mt = 0; mt < MT; mt++) {
            #pragma unroll
            for (int r = 0; r < 4; r++) {
                int m = bm0 + wm * (MT * 16) + mt * 16 + quad * 4 + r;
                float v = acc[mt][nt][r] + bv;
                if (epi_mode == 1) {
                    v *= E[(size_t)(m / m_div) * N + n];
                } else if (epi_mode == 2) {
                    float g = gate[m];
                    v = g * mi1[(size_t)m * N + n] + (1.f - g) * v;
                }
                if (out_f32) ((float*)Cout)[(size_t)m * N + n] = v;
                else         ((u16*)Cout)[(size_t)m * N + n] = f2b(v);
            }
        }
    }
}

// ---------------------------------------------------------------- fused read-path
// Per 64-row slab: G1 = (kbf@Wrk + brk)*E1 -> LDS;  G2 = ([G1|kbf]@Wrik + brik)*E2 -> LDS;
// G3 = G2@Wrci + brci -> rai (HBM).  A for G2a/G3 read straight from LDS g_tile.
// R4 structure (LDS-staged operands, counted-vmcnt barrier + lgkm-only trailing barrier)
// with 1x8 wave layout: each of 8 waves owns all 64 rows x 64 cols -> per-step LDS reads
// 64KB (4 A-frags shared + 4 own B-frags) vs 80KB for 2x4. setprio(1) around MFMA cluster.
__global__ __launch_bounds__(512, 2) void fused_read(
    const u16* __restrict__ kbf, int M,
    const u16* __restrict__ Wrk,  const float* __restrict__ brk,  const float* __restrict__ E1,
    const u16* __restrict__ Wrik, const float* __restrict__ brik, const float* __restrict__ E2,
    const u16* __restrict__ Wrci, const float* __restrict__ brci,
    u16* __restrict__ rai)
{
    __shared__ __align__(16) char smem[139264];
    short* g_tile = (short*)smem;                     // [64][512] shorts, 16B-chunk XOR swizzle
    short* stgbase = (short*)(smem + 65536);          // 2 stage bufs of 18432 shorts each

    int tid = threadIdx.x, wave = tid >> 6, lane = tid & 63;
    int lrow = lane & 15, quad = lane >> 4;
    int r16 = lane >> 2, cc = lane & 3;
    int sw = (r16 >> 1) & 3;
    int coff = (cc ^ sw) * 8;                         // shorts
    int sw2 = (lrow >> 1) & 3;

    int bid = blockIdx.x;
    { int nb = gridDim.x; if ((nb & 7) == 0) { int x = bid & 7, j = bid >> 3; bid = x * (nb >> 3) + j; } }
    int bm0 = bid * 64;

    // ---- staging (identical to R4: 16 rows x 64B per DMA) ----
    auto stageB = [&](short* bf, const u16* Wt, int ldk, int k0) {
        short* Bs = bf + 2048;
        #pragma unroll
        for (int i = 0; i < 4; i++) {
            int br = wave * 64 + i * 16;
            gl2lds(Wt + (size_t)(br + r16) * ldk + k0 + coff, Bs + br * 32);
        }
    };
    auto stageA = [&](short* bf, int k0) {
        if (wave < 4) {
            int ar = wave * 16;
            gl2lds(kbf + (size_t)(bm0 + ar + r16) * 512 + k0 + coff, bf + ar * 32);
        }
    };

    f4 acc[4][4];
    auto clr = [&]() {
        #pragma unroll
        for (int t = 0; t < 4; t++)
            #pragma unroll
            for (int nt = 0; nt < 4; nt++)
                acc[t][nt] = (f4){0.f, 0.f, 0.f, 0.f};
    };

    // one K-step: aMode 0 = A from staged buf; 1 = A from g_tile at chunk base kc0
    auto kstep = [&](const short* bf, int aMode, int kc0) {
        short8 af[4], bfrag[4];
        #pragma unroll
        for (int t = 0; t < 4; t++) {
            int R = t * 16 + lrow;
            if (aMode == 0)
                af[t] = *(const short8*)&bf[R * 32 + (quad ^ sw2) * 8];
            else {
                int kc = kc0 + quad;
                af[t] = *(const short8*)&g_tile[R * 512 + ((kc ^ (R & 7)) << 3)];
            }
        }
        const short* Bs = bf + 2048;
        #pragma unroll
        for (int nt = 0; nt < 4; nt++)
            bfrag[nt] = *(const short8*)&Bs[(wave * 64 + nt * 16 + lrow) * 32 + (quad ^ sw2) * 8];
        __builtin_amdgcn_s_setprio(1);
        #pragma unroll
        for (int t = 0; t < 4; t++)
            #pragma unroll
            for (int nt = 0; nt < 4; nt++)
                acc[t][nt] = __builtin_amdgcn_mfma_f32_16x16x32_bf16(
                    af[t], bfrag[nt], acc[t][nt], 0, 0, 0);
        __builtin_amdgcn_s_setprio(0);
    };

    // accum -> (acc+bias)*E -> bf16 -> g_tile (swizzled chunks)
    int bt0 = bm0 / 196, bt1 = (bm0 + 63) / 196;
    int rsw = (bt1 != bt0) ? (bt1 * 196 - bm0) : 64;
    auto epi_to_gtile = [&](const float* bias, const float* E) {
        #pragma unroll
        for (int nt = 0; nt < 4; nt++) {
            int n = wave * 64 + nt * 16 + lrow;
            float bv = bias[n];
            float e0 = E[(size_t)bt0 * 512 + n];
            float e1 = E[(size_t)bt1 * 512 + n];
            #pragma unroll
            for (int t = 0; t < 4; t++)
                #pragma unroll
                for (int r = 0; r < 4; r++) {
                    int row = t * 16 + quad * 4 + r;
                    float e = (row < rsw) ? e0 : e1;
                    u16 h = f2b((acc[t][nt][r] + bv) * e);
                    int chunk = (n >> 3) ^ (row & 7);
                    g_tile[row * 512 + chunk * 8 + (n & 7)] = (short)h;
                }
        }
    };

    // ================= G1: kbf @ Wrk =================
    clr();
    stageA(stgbase, 0); stageB(stgbase, Wrk, 512, 0);
    for (int kt = 0; kt < 16; kt++) {
        short* cur = stgbase + (kt & 1) * 18432;
        short* nxt = stgbase + ((kt & 1) ^ 1) * 18432;
        if (kt + 1 < 16) {
            stageA(nxt, (kt + 1) * 32); stageB(nxt, Wrk, 512, (kt + 1) * 32);
            if (wave < 4) asm volatile("s_waitcnt vmcnt(5) lgkmcnt(0)\ns_barrier" ::: "memory");
            else          asm volatile("s_waitcnt vmcnt(4) lgkmcnt(0)\ns_barrier" ::: "memory");
        } else
            asm volatile("s_waitcnt vmcnt(0) lgkmcnt(0)\ns_barrier" ::: "memory");
        kstep(cur, 0, 0);
        asm volatile("s_waitcnt lgkmcnt(0)\ns_barrier" ::: "memory");
    }
    epi_to_gtile(brk, E1);
    __syncthreads();

    // ================= G2a: g_tile(=G1) @ Wrik[k<512] =================
    clr();
    stageB(stgbase, Wrik, 1024, 0);
    for (int kt = 0; kt < 16; kt++) {
        short* cur = stgbase + (kt & 1) * 18432;
        short* nxt = stgbase + ((kt & 1) ^ 1) * 18432;
        if (kt + 1 < 16) {
            stageB(nxt, Wrik, 1024, (kt + 1) * 32);
            asm volatile("s_waitcnt vmcnt(4) lgkmcnt(0)\ns_barrier" ::: "memory");
        } else
            asm volatile("s_waitcnt vmcnt(0) lgkmcnt(0)\ns_barrier" ::: "memory");
        kstep(cur, 1, kt * 4);
        asm volatile("s_waitcnt lgkmcnt(0)\ns_barrier" ::: "memory");
    }
    // ================= G2b: kbf @ Wrik[k>=512] =================
    stageA(stgbase, 0); stageB(stgbase, Wrik, 1024, 512);
    for (int kt = 0; kt < 16; kt++) {
        short* cur = stgbase + (kt & 1) * 18432;
        short* nxt = stgbase + ((kt & 1) ^ 1) * 18432;
        if (kt + 1 < 16) {
            stageA(nxt, (kt + 1) * 32); stageB(nxt, Wrik, 1024, 512 + (kt + 1) * 32);
            if (wave < 4) asm volatile("s_waitcnt vmcnt(5) lgkmcnt(0)\ns_barrier" ::: "memory");
            else          asm volatile("s_waitcnt vmcnt(4) lgkmcnt(0)\ns_barrier" ::: "memory");
        } else
            asm volatile("s_waitcnt vmcnt(0) lgkmcnt(0)\ns_barrier" ::: "memory");
        kstep(cur, 0, 0);
        asm volatile("s_waitcnt lgkmcnt(0)\ns_barrier" ::: "memory");
    }
    epi_to_gtile(brik, E2);
    __syncthreads();

    // ================= G3: g_tile(=G2) @ Wrci =================
    clr();
    stageB(stgbase, Wrci, 512, 0);
    for (int kt = 0; kt < 16; kt++) {
        short* cur = stgbase + (kt & 1) * 18432;
        short* nxt = stgbase + ((kt & 1) ^ 1) * 18432;
        if (kt + 1 < 16) {
            stageB(nxt, Wrci, 512, (kt + 1) * 32);
            asm volatile("s_waitcnt vmcnt(4) lgkmcnt(0)\ns_barrier" ::: "memory");
        } else
            asm volatile("s_waitcnt vmcnt(0) lgkmcnt(0)\ns_barrier" ::: "memory");
        kstep(cur, 1, kt * 4);
        asm volatile("s_waitcnt lgkmcnt(0)\ns_barrier" ::: "memory");
    }
    // final epilogue: +brci, linear bf16 into g_tile, then coalesced copy out
    #pragma unroll
    for (int nt = 0; nt < 4; nt++) {
        int n = wave * 64 + nt * 16 + lrow;
        float bv = brci[n];
        #pragma unroll
        for (int t = 0; t < 4; t++)
            #pragma unroll
            for (int r = 0; r < 4; r++) {
                int row = t * 16 + quad * 4 + r;
                g_tile[row * 512 + n] = (short)f2b(acc[t][nt][r] + bv);
            }
    }
    __syncthreads();
    #pragma unroll
    for (int p = 0; p < 8; p++) {
        int idx = p * 512 + tid;                 // 16B units, 4096 total
        short8 v = *(const short8*)&g_tile[idx * 8];
        *(short8*)&rai[(size_t)bm0 * 512 + (size_t)idx * 8] = v;
    }
}

// ---------------------------------------------------------------- control attention
__global__ __launch_bounds__(256) void control_attn(
    const float* __restrict__ cqi, const float* __restrict__ cws,
    const float* __restrict__ Wcai, const float* __restrict__ bcai,
    float* __restrict__ ci_f32, float* __restrict__ ci_out)
{
    int b = blockIdx.x, tid = threadIdx.x;
    __shared__ float tW[512];
    __shared__ float p[128];
    __shared__ float inv_l;
    for (int d = tid; d < 512; d += 256)
        tW[d] = cqi[(size_t)b * 512 + d] * Wcai[d];
    __syncthreads();
    int wave = tid >> 6, lane = tid & 63;
    const float* cwsb = cws + (size_t)b * 128 * 512;
    for (int s = wave; s < 128; s += 4) {
        const float* row = cwsb + (size_t)s * 512 + lane * 8;
        float acc = 0.f;
        #pragma unroll
        for (int j = 0; j < 8; j++) acc += tW[lane * 8 + j] * row[j];
        acc = wave_reduce_sum(acc);
        if (lane == 0) p[s] = acc + bcai[0];
    }
    __syncthreads();
    if (tid == 0) {
        float m = -1e30f;
        for (int s = 0; s < 128; s++) m = fmaxf(m, p[s]);
        float l = 0.f;
        for (int s = 0; s < 128; s++) { float e = __expf(p[s] - m); p[s] = e; l += e; }
        inv_l = 1.f / l;
    }
    __syncthreads();
    float inv = inv_l;
    for (int d = tid; d < 512; d += 256) {
        float acc = 0.f;
        for (int s = 0; s < 128; s++) acc += p[s] * cwsb[(size_t)s * 512 + d];
        acc *= inv;
        ci_f32[(size_t)b * 512 + d] = acc;
        ci_out[(size_t)b * 512 + d] = acc;
    }
}

// ---------------------------------------------------------------- read reduce
__global__ __launch_bounds__(256) void read_reduce(
    const u16* __restrict__ rai, const u16* __restrict__ Kb, u16* __restrict__ ri)
{
    int b = blockIdx.x >> 1;
    int d = ((blockIdx.x & 1) << 8) + threadIdx.x;
    const u16* rb = rai + (size_t)b * 196 * 512 + d;
    const u16* kb = Kb + (size_t)b * 196 * 512 + d;
    float m1[14], il1[14];
    #pragma unroll
    for (int w = 0; w < 14; w++) {
        float m = -1e30f, s = 0.f;
        #pragma unroll
        for (int h = 0; h < 14; h++) {
            float v = b2f(rb[(size_t)(h * 14 + w) * 512]);
            float nm = fmaxf(m, v);
            s = s * __expf(m - nm) + __expf(v - nm);
            m = nm;
        }
        m1[w] = m; il1[w] = 1.f / s;
    }
    float acc = 0.f;
    #pragma unroll
    for (int h = 0; h < 14; h++) {
        float pv[14], ss = 0.f;
        #pragma unroll
        for (int w = 0; w < 14; w++) {
            float pr = __expf(b2f(rb[(size_t)(h * 14 + w) * 512]) - m1[w]) * il1[w];
            float e = __expf(pr);
            pv[w] = e; ss += e;
        }
        float il2 = 1.f / ss;
        #pragma unroll
        for (int w = 0; w < 14; w++)
            acc += pv[w] * il2 * b2f(kb[(size_t)(h * 14 + w) * 512]);
    }
    ri[(size_t)b * 512 + d] = f2b(acc);
}

// ---------------------------------------------------------------- write attention + gate
__global__ __launch_bounds__(256) void write_attn(
    const float* __restrict__ ci_f32, const float* __restrict__ C_past,
    const float* __restrict__ M_past,
    const float* __restrict__ Wwcc, const float* __restrict__ bwcc,
    const float* __restrict__ Wwci, const float* __restrict__ bwci,
    u16* __restrict__ mi_sa, float* __restrict__ gate)
{
    int b = blockIdx.x, tid = threadIdx.x;
    __shared__ float c[512];
    __shared__ float pt[12];
    __shared__ float red[256];
    for (int d = tid; d < 512; d += 256) c[d] = ci_f32[(size_t)b * 512 + d];
    __syncthreads();
    float g = 0.f;
    for (int d = tid; d < 512; d += 256) g += c[d] * Wwci[d];
    red[tid] = g;
    __syncthreads();
    for (int s = 128; s > 0; s >>= 1) {
        if (tid < s) red[tid] += red[tid + s];
        __syncthreads();
    }
    int wave = tid >> 6, lane = tid & 63;
    const float* cp = C_past + (size_t)b * 12 * 512;
    for (int t = wave; t < 12; t += 4) {
        float acc = 0.f;
        #pragma unroll
        for (int j = 0; j < 8; j++) {
            int d = lane * 8 + j;
            acc += c[d] * Wwcc[d] * cp[(size_t)t * 512 + d];
        }
        acc = wave_reduce_sum(acc);
        if (lane == 0) pt[t] = acc + bwcc[0];
    }
    __syncthreads();
    if (tid == 0) {
        float m = -1e30f;
        for (int t = 0; t < 12; t++) m = fmaxf(m, pt[t]);
        float l = 0.f;
        for (int t = 0; t < 12; t++) { float e = __expf(pt[t] - m); pt[t] = e; l += e; }
        float invl = 1.f / l;
        for (int t = 0; t < 12; t++) pt[t] *= invl;
        gate[b] = 1.f / (1.f + __expf(-(red[0] + bwci[0])));
    }
    __syncthreads();
    const float* mp = M_past + (size_t)b * 12 * 512;
    for (int d = tid; d < 512; d += 256) {
        float acc = 0.f;
        #pragma unroll
        for (int t = 0; t < 12; t++) acc += pt[t] * mp[(size_t)t * 512 + d];
        mi_sa[(size_t)b * 512 + d] = f2b(acc);
    }
}

// ---------------------------------------------------------------- launch
extern "C" void kernel_launch(void* const* d_in, const int* in_sizes, int n_in,
                              void* d_out, int out_size, void* d_ws, size_t ws_size,
                              hipStream_t stream) {
    (void)in_sizes; (void)n_in; (void)out_size;
    const int B = 256, D = 512, HW = 196;

    const float* ci_1   = (const float*)d_in[0];
    const float* mi_1   = (const float*)d_in[1];
    const float* q      = (const float*)d_in[2];
    const float* cws    = (const float*)d_in[3];
    const float* Kin    = (const float*)d_in[4];
    const float* C_past = (const float*)d_in[5];
    const float* M_past = (const float*)d_in[6];
    const float* W_cq   = (const float*)d_in[7];
    const float* b_cq   = (const float*)d_in[8];
    const float* W_cqi  = (const float*)d_in[9];
    const float* b_cqi  = (const float*)d_in[10];
    const float* W_cai  = (const float*)d_in[11];
    const float* b_cai  = (const float*)d_in[12];
    const float* W_rm   = (const float*)d_in[13];
    const float* b_rm   = (const float*)d_in[14];
    const float* W_rk   = (const float*)d_in[15];
    const float* b_rk   = (const float*)d_in[16];
    const float* W_rik  = (const float*)d_in[17];
    const float* b_rik  = (const float*)d_in[18];
    const float* W_rci  = (const float*)d_in[19];
    const float* b_rci  = (const float*)d_in[20];
    const float* W_wrm  = (const float*)d_in[21];
    const float* b_wrm  = (const float*)d_in[22];
    const float* W_wcc  = (const float*)d_in[23];
    const float* b_wcc  = (const float*)d_in[24];
    const float* W_wsa  = (const float*)d_in[25];
    const float* b_wsa  = (const float*)d_in[26];
    const float* W_winfo= (const float*)d_in[27];
    const float* b_winfo= (const float*)d_in[28];
    const float* W_wci  = (const float*)d_in[29];
    const float* b_wci  = (const float*)d_in[30];

    float* out_ci = (float*)d_out;
    float* out_mi = (float*)d_out + (size_t)B * D;

    char* ws = (char*)d_ws;
    size_t off = 0;
    auto alloc = [&](size_t bytes) -> void* {
        void* p = ws + off; off += (bytes + 255) & ~(size_t)255; return p;
    };
    u16* wt_cq    = (u16*)alloc((size_t)D * D * 2);
    u16* wt_cqi   = (u16*)alloc((size_t)D * 2 * D * 2);
    u16* wt_rm    = (u16*)alloc((size_t)D * D * 2);
    u16* wt_rk    = (u16*)alloc((size_t)D * D * 2);
    u16* wt_rik   = (u16*)alloc((size_t)D * 2 * D * 2);
    u16* wt_rci   = (u16*)alloc((size_t)D * D * 2);
    u16* wt_wrm   = (u16*)alloc((size_t)D * 2 * D * 2);
    u16* wt_wsi   = (u16*)alloc((size_t)D * 2 * D * 2);
    u16* qb       = (u16*)alloc((size_t)B * D * 2);
    u16* cib      = (u16*)alloc((size_t)B * D * 2);
    u16* mib      = (u16*)alloc((size_t)B * D * 2);
    u16* qi_buf   = (u16*)alloc((size_t)B * D * 2);
    float* cqi_f32= (float*)alloc((size_t)B * D * 4);
    float* rm_f32 = (float*)alloc((size_t)B * D * 4);
    float* ci_f32 = (float*)alloc((size_t)B * D * 4);
    u16* ri_buf   = (u16*)alloc((size_t)B * D * 2);
    u16* misa_buf = (u16*)alloc((size_t)B * D * 2);
    u16* minfo_buf= (u16*)alloc((size_t)B * D * 2);
    float* gate_b = (float*)alloc((size_t)B * 4);

    int chunk_b = 256;
    while (chunk_b > 32) {
        size_t need = off + 2 * (((size_t)chunk_b * HW * D * 2 + 255) & ~(size_t)255);
        if (need <= ws_size) break;
        chunk_b >>= 1;
    }
    u16* kbf  = (u16*)alloc((size_t)chunk_b * HW * D * 2);
    u16* big1 = (u16*)alloc((size_t)chunk_b * HW * D * 2);

    dim3 tb(32, 8);
    transpose_k<<<dim3(D / 32, D / 32), tb, 0, stream>>>(W_cq,   wt_cq,  D,     D, D,     0);
    transpose_k<<<dim3(2 * D / 32, D / 32), tb, 0, stream>>>(W_cqi, wt_cqi, 2 * D, D, 2 * D, 0);
    transpose_k<<<dim3(D / 32, D / 32), tb, 0, stream>>>(W_rm,   wt_rm,  D,     D, D,     0);
    transpose_k<<<dim3(D / 32, D / 32), tb, 0, stream>>>(W_rk,   wt_rk,  D,     D, D,     0);
    transpose_k<<<dim3(2 * D / 32, D / 32), tb, 0, stream>>>(W_rik, wt_rik, 2 * D, D, 2 * D, 0);
    transpose_k<<<dim3(D / 32, D / 32), tb, 0, stream>>>(W_rci,  wt_rci, D,     D, D,     0);
    transpose_k<<<dim3(2 * D / 32, D / 32), tb, 0, stream>>>(W_wrm, wt_wrm, 2 * D, D, 2 * D, 0);
    transpose_k<<<dim3(D / 32, D / 32), tb, 0, stream>>>(W_wsa,  wt_wsi, D,     D, 2 * D, 0);
    transpose_k<<<dim3(D / 32, D / 32), tb, 0, stream>>>(W_winfo,wt_wsi, D,     D, 2 * D, D);

    int nbd = B * D;
    conv_f32_bf16<<<nbd / 1024, 256, 0, stream>>>(q, qb, nbd);
    conv_f32_bf16<<<nbd / 1024, 256, 0, stream>>>(ci_1, cib, nbd);
    conv_f32_bf16<<<nbd / 1024, 256, 0, stream>>>(mi_1, mib, nbd);

    dim3 gsmall(D / 64, B / 64); // (8, 4) = 32 blocks

    gemm_mfma<2,2><<<gsmall, 256, 0, stream>>>(qb, nullptr, B, D, 0, D, wt_cq, b_cq, nullptr,
                                               0, nullptr, 1, nullptr, nullptr, qi_buf, 0);
    gemm_mfma<2,2><<<gsmall, 256, 0, stream>>>(cib, qi_buf, B, D, D, D, wt_cqi, b_cqi, nullptr,
                                               0, nullptr, 1, nullptr, nullptr, cqi_f32, 1);
    control_attn<<<B, 256, 0, stream>>>(cqi_f32, cws, W_cai, b_cai, ci_f32, out_ci);
    gemm_mfma<2,2><<<gsmall, 256, 0, stream>>>(mib, nullptr, B, D, 0, D, wt_rm, b_rm, nullptr,
                                               0, nullptr, 1, nullptr, nullptr, rm_f32, 1);

    for (int c = 0; c < B; c += chunk_b) {
        int mrows = chunk_b * HW;
        const float* Kc = Kin + (size_t)c * HW * D;
        conv_f32_bf16<<<(mrows * D) / 1024, 256, 0, stream>>>(Kc, kbf, mrows * D);
        fused_read<<<mrows / 64, 512, 0, stream>>>(
            kbf, mrows,
            wt_rk,  b_rk,  rm_f32 + (size_t)c * D,
            wt_rik, b_rik, ci_f32 + (size_t)c * D,
            wt_rci, b_rci,
            big1);
        read_reduce<<<chunk_b * 2, 256, 0, stream>>>(big1, kbf, ri_buf + (size_t)c * D);
    }

    gemm_mfma<2,2><<<gsmall, 256, 0, stream>>>(ri_buf, mib, B, D, D, D, wt_wrm, b_wrm, nullptr,
                                               0, nullptr, 1, nullptr, nullptr, minfo_buf, 0);
    write_attn<<<B, 256, 0, stream>>>(ci_f32, C_past, M_past, W_wcc, b_wcc, W_wci, b_wci,
                                      misa_buf, gate_b);
    gemm_mfma<2,2><<<gsmall, 256, 0, stream>>>(misa_buf, minfo_buf, B, D, D, D, wt_wsi,
                                               b_wsa, b_winfo, 2, nullptr, 1, gate_b, mi_1,
                                               out_mi, 1);
}

// Round 8
// 591.526 us; speedup vs baseline: 1.5908x; 1.0159x over previous
//
#include <hip/hip_runtime.h>
#include <hip/hip_bf16.h>

typedef unsigned short u16;
typedef __attribute__((ext_vector_type(8))) short short8;
typedef __attribute__((ext_vector_type(4))) float f4;

static __device__ __forceinline__ float b2f(u16 u) {
    union { unsigned int i; float f; } x; x.i = ((unsigned int)u) << 16; return x.f;
}
static __device__ __forceinline__ u16 f2b(float f) {
    union { float f; unsigned int i; } x; x.f = f;
    unsigned int r = x.i + 0x7fffu + ((x.i >> 16) & 1u);
    return (u16)(r >> 16);
}
static __device__ __forceinline__ float wave_reduce_sum(float v) {
    #pragma unroll
    for (int off = 32; off > 0; off >>= 1) v += __shfl_down(v, off, 64);
    return v;
}
// async global->LDS, 16B per lane; lane i lands at ldsbase + i*16
static __device__ __forceinline__ void gl2lds(const void* g, void* l) {
    __builtin_amdgcn_global_load_lds(
        (const __attribute__((address_space(1))) void*)g,
        (__attribute__((address_space(3))) void*)l, 16, 0, 0);
}

// ---------------------------------------------------------------- f32 -> bf16 convert (big buffers)
__global__ __launch_bounds__(256) void conv_f32_bf16(
    const float* __restrict__ src, u16* __restrict__ dst, int n)
{
    int i = (blockIdx.x * 256 + threadIdx.x) * 4;
    if (i >= n) return;
    float4 v = *(const float4*)(src + i);
    union { u16 u[4]; uint2 d; } o;
    o.u[0] = f2b(v.x); o.u[1] = f2b(v.y); o.u[2] = f2b(v.z); o.u[3] = f2b(v.w);
    *(uint2*)(dst + i) = o.d;
}

// three B*D convs in one launch (128 blocks each)
__global__ __launch_bounds__(256) void conv3_f32_bf16(
    const float* __restrict__ s0, const float* __restrict__ s1, const float* __restrict__ s2,
    u16* __restrict__ d0, u16* __restrict__ d1, u16* __restrict__ d2)
{
    int which = blockIdx.x >> 7;
    int i = ((blockIdx.x & 127) * 256 + threadIdx.x) * 4;
    const float* s = (which == 0) ? s0 : (which == 1) ? s1 : s2;
    u16* d = (which == 0) ? d0 : (which == 1) ? d1 : d2;
    float4 v = *(const float4*)(s + i);
    union { u16 u[4]; uint2 d; } o;
    o.u[0] = f2b(v.x); o.u[1] = f2b(v.y); o.u[2] = f2b(v.z); o.u[3] = f2b(v.w);
    *(uint2*)(d + i) = o.d;
}

// ---------------------------------------------------------------- batched transpose f32 -> bf16
// all 9 weight transposes in ONE launch; N (input cols) == 512 for all.
struct TBatch {
    const float* in[9];
    u16* out[9];
    int K[9];
    int ostride[9];
    int koff[9];
    int tbase[9];     // start tile index per weight; tiles = (K/32)*16
};

__global__ __launch_bounds__(256) void transpose_batch(TBatch a)
{
    __shared__ float t[32][33];
    int b = blockIdx.x;
    int w = 0;
    #pragma unroll
    for (int i = 1; i < 9; i++) if (b >= a.tbase[i]) w = i;
    int lt = b - a.tbase[w];
    int kb = (lt >> 4) * 32, nb = (lt & 15) * 32;
    const float* in = a.in[w];
    u16* out = a.out[w];
    int N = 512, ostride = a.ostride[w], koff = a.koff[w];
    int tx = threadIdx.x, ty = threadIdx.y; // blockDim (32,8)
    #pragma unroll
    for (int i = 0; i < 4; i++)
        t[ty + i * 8][tx] = in[(size_t)(kb + ty + i * 8) * N + nb + tx];
    __syncthreads();
    #pragma unroll
    for (int i = 0; i < 4; i++)
        out[(size_t)(nb + ty + i * 8) * ostride + koff + kb + tx] =
            f2b(t[tx][ty + i * 8]);
}

// ---------------------------------------------------------------- small MFMA GEMM (<2,2> use)
template<int MT, int NT>   // block tile = (MT*32) x (NT*32); 4 waves in 2x2
__global__ __launch_bounds__(256) void gemm_mfma(
    const u16* __restrict__ A0, const u16* __restrict__ A1,
    int M, int K0, int K1, int N,
    const u16* __restrict__ Bt,
    const float* __restrict__ bias0, const float* __restrict__ bias1,
    int epi_mode, const float* __restrict__ E, int m_div,
    const float* __restrict__ gate, const float* __restrict__ mi1,
    void* __restrict__ Cout, int out_f32)
{
    constexpr int BM = MT * 32, BN = NT * 32;
    constexpr int STG = (BM + BN) * 32;          // shorts per stage
    constexpr int NPF = MT / 2 + NT / 2;         // DMA loads per stage per wave
    constexpr int STAGE_B = 3 * STG * 2;
    __shared__ __align__(16) char smem[STAGE_B];
    short* stg = (short*)smem;

    int tid  = threadIdx.x;
    int wave = tid >> 6, lane = tid & 63;
    int wm = wave >> 1, wn = wave & 1;
    int lrow = lane & 15, quad = lane >> 4;

    int gx = gridDim.x, gy = gridDim.y;
    int bx = blockIdx.x, by = blockIdx.y;
    if ((gy & 7) == 0) {
        int lin = by * gx + bx;
        int xcd = lin & 7, j = lin >> 3;
        by = xcd * (gy >> 3) + j / gx;
        bx = j % gx;
    }
    int bm0 = by * BM, bn0 = bx * BN;
    int Ktot = K0 + K1;
    int KT = Ktot >> 5;

    int r16 = lane >> 2, cc = lane & 3;
    int sw = (r16 >> 1) & 3;
    int coff = (cc ^ sw) * 8;

    auto stage = [&](int s, int k0) {
        const u16* asrc; int lda;
        if (k0 < K0) { asrc = A0 + k0; lda = K0; }
        else         { asrc = A1 + (k0 - K0); lda = K1; }
        short* As = stg + s * STG;
        short* Bs = As + BM * 32;
        #pragma unroll
        for (int i = 0; i < MT / 2; i++) {
            int ar = wave * (BM / 4) + 16 * i;
            gl2lds(asrc + (size_t)(bm0 + ar + r16) * lda + coff, As + ar * 32);
        }
        #pragma unroll
        for (int i = 0; i < NT / 2; i++) {
            int br = wave * (BN / 4) + 16 * i;
            gl2lds(Bt + (size_t)(bn0 + br + r16) * Ktot + k0 + coff, Bs + br * 32);
        }
    };

    f4 acc[MT][NT];
    #pragma unroll
    for (int i = 0; i < MT; i++)
        #pragma unroll
        for (int j = 0; j < NT; j++)
            acc[i][j] = (f4){0.f, 0.f, 0.f, 0.f};

    stage(0, 0);
    if (KT > 1) stage(1, 32);
    int sb = 0;
    int sw2 = (lrow >> 1) & 3;
    for (int kt = 0; kt < KT; kt++) {
        if (kt + 1 < KT) {
            if constexpr (NPF == 2)
                asm volatile("s_waitcnt vmcnt(2) lgkmcnt(0)\ns_barrier" ::: "memory");
            else
                asm volatile("s_waitcnt vmcnt(0) lgkmcnt(0)\ns_barrier" ::: "memory");
        } else {
            asm volatile("s_waitcnt vmcnt(0) lgkmcnt(0)\ns_barrier" ::: "memory");
        }
        const short* Ab = stg + sb * STG;
        const short* Bb = Ab + BM * 32;
        if (kt + 2 < KT) {
            int s2 = sb + 2; if (s2 >= 3) s2 -= 3;
            stage(s2, (kt + 2) * 32);
        }
        short8 af[MT], bfr[NT];
        #pragma unroll
        for (int mt = 0; mt < MT; mt++)
            af[mt] = *(const short8*)&Ab[(wm * (MT * 16) + mt * 16 + lrow) * 32 + (quad ^ sw2) * 8];
        #pragma unroll
        for (int nt = 0; nt < NT; nt++)
            bfr[nt] = *(const short8*)&Bb[(wn * (NT * 16) + nt * 16 + lrow) * 32 + (quad ^ sw2) * 8];
        #pragma unroll
        for (int mt = 0; mt < MT; mt++)
            #pragma unroll
            for (int nt = 0; nt < NT; nt++)
                acc[mt][nt] = __builtin_amdgcn_mfma_f32_16x16x32_bf16(
                    af[mt], bfr[nt], acc[mt][nt], 0, 0, 0);
        sb = (sb + 1 == 3) ? 0 : sb + 1;
    }

    // direct epilogue (small tiles)
    #pragma unroll
    for (int nt = 0; nt < NT; nt++) {
        int n = bn0 + wn * (NT * 16) + nt * 16 + lrow;
        float bv = 0.f;
        if (bias0) bv += bias0[n];
        if (bias1) bv += bias1[n];
        #pragma unroll
        for (int mt = 0; mt < MT; mt++) {
            #pragma unroll
            for (int r = 0; r < 4; r++) {
                int m = bm0 + wm * (MT * 16) + mt * 16 + quad * 4 + r;
                float v = acc[mt][nt][r] + bv;
                if (epi_mode == 1) {
                    v *= E[(size_t)(m / m_div) * N + n];
                } else if (epi_mode == 2) {
                    float g = gate[m];
                    v = g * mi1[(size_t)m * N + n] + (1.f - g) * v;
                }
                if (out_f32) ((float*)Cout)[(size_t)m * N + n] = v;
                else         ((u16*)Cout)[(size_t)m * N + n] = f2b(v);
            }
        }
    }
}

// ---------------------------------------------------------------- fused read-path
// Per 64-row slab: G1 = (kbf@Wrk + brk)*E1 -> LDS;  G2 = ([G1|kbf]@Wrik + brik)*E2 -> LDS;
// G3 = G2@Wrci + brci -> rai (HBM).  A for G2a/G3 read straight from LDS g_tile.
// 1024 threads = 16 waves (2 row-groups x 8 col-groups) -> 4 waves/SIMD for latency hiding
// (139KB LDS caps at 1 block/CU).  R4-proven staging + counted-vmcnt barrier skeleton.
__global__ __launch_bounds__(1024, 4) void fused_read(
    const u16* __restrict__ kbf, int M,
    const u16* __restrict__ Wrk,  const float* __restrict__ brk,  const float* __restrict__ E1,
    const u16* __restrict__ Wrik, const float* __restrict__ brik, const float* __restrict__ E2,
    const u16* __restrict__ Wrci, const float* __restrict__ brci,
    u16* __restrict__ rai)
{
    __shared__ __align__(16) char smem[139264];
    short* g_tile = (short*)smem;                     // [64][512] shorts, 16B-chunk XOR swizzle
    short* stgbase = (short*)(smem + 65536);          // 2 stage bufs of 18432 shorts each

    int tid = threadIdx.x, wave = tid >> 6, lane = tid & 63;
    int wr = wave >> 3, wc = wave & 7;                // 2 x 8 wave grid
    int lrow = lane & 15, quad = lane >> 4;
    int r16 = lane >> 2, cc = lane & 3;
    int sw = (r16 >> 1) & 3;
    int coff = (cc ^ sw) * 8;                         // shorts
    int sw2 = (lrow >> 1) & 3;

    int bid = blockIdx.x;
    { int nb = gridDim.x; if ((nb & 7) == 0) { int x = bid & 7, j = bid >> 3; bid = x * (nb >> 3) + j; } }
    int bm0 = bid * 64;

    // ---- staging: B rows split 2/wave over 16 waves; A rows on waves 0-3 ----
    auto stageB = [&](short* bf, const u16* Wt, int ldk, int k0) {
        short* Bs = bf + 2048;
        #pragma unroll
        for (int i = 0; i < 2; i++) {
            int br = wave * 32 + i * 16;
            gl2lds(Wt + (size_t)(br + r16) * ldk + k0 + coff, Bs + br * 32);
        }
    };
    auto stageA = [&](short* bf, int k0) {
        if (wave < 4) {
            int ar = wave * 16;
            gl2lds(kbf + (size_t)(bm0 + ar + r16) * 512 + k0 + coff, bf + ar * 32);
        }
    };

    f4 acc[2][4];
    auto clr = [&]() {
        #pragma unroll
        for (int t = 0; t < 2; t++)
            #pragma unroll
            for (int nt = 0; nt < 4; nt++)
                acc[t][nt] = (f4){0.f, 0.f, 0.f, 0.f};
    };

    // one K-step: aMode 0 = A from staged buf; 1 = A from g_tile at chunk base kc0
    auto kstep = [&](const short* bf, int aMode, int kc0) {
        short8 af[2], bfrag[4];
        #pragma unroll
        for (int t = 0; t < 2; t++) {
            int R = wr * 32 + t * 16 + lrow;
            if (aMode == 0)
                af[t] = *(const short8*)&bf[R * 32 + (quad ^ sw2) * 8];
            else {
                int kc = kc0 + quad;
                af[t] = *(const short8*)&g_tile[R * 512 + ((kc ^ (R & 7)) << 3)];
            }
        }
        const short* Bs = bf + 2048;
        #pragma unroll
        for (int nt = 0; nt < 4; nt++)
            bfrag[nt] = *(const short8*)&Bs[(wc * 64 + nt * 16 + lrow) * 32 + (quad ^ sw2) * 8];
        __builtin_amdgcn_s_setprio(1);
        #pragma unroll
        for (int t = 0; t < 2; t++)
            #pragma unroll
            for (int nt = 0; nt < 4; nt++)
                acc[t][nt] = __builtin_amdgcn_mfma_f32_16x16x32_bf16(
                    af[t], bfrag[nt], acc[t][nt], 0, 0, 0);
        __builtin_amdgcn_s_setprio(0);
    };

    // accum -> (acc+bias)*E -> bf16 -> g_tile (swizzled chunks)
    int bt0 = bm0 / 196, bt1 = (bm0 + 63) / 196;
    int rsw = (bt1 != bt0) ? (bt1 * 196 - bm0) : 64;
    auto epi_to_gtile = [&](const float* bias, const float* E) {
        #pragma unroll
        for (int nt = 0; nt < 4; nt++) {
            int n = wc * 64 + nt * 16 + lrow;
            float bv = bias[n];
            float e0 = E[(size_t)bt0 * 512 + n];
            float e1 = E[(size_t)bt1 * 512 + n];
            #pragma unroll
            for (int t = 0; t < 2; t++)
                #pragma unroll
                for (int r = 0; r < 4; r++) {
                    int row = wr * 32 + t * 16 + quad * 4 + r;
                    float e = (row < rsw) ? e0 : e1;
                    u16 h = f2b((acc[t][nt][r] + bv) * e);
                    int chunk = (n >> 3) ^ (row & 7);
                    g_tile[row * 512 + chunk * 8 + (n & 7)] = (short)h;
                }
        }
    };

    // ================= G1: kbf @ Wrk =================
    clr();
    stageA(stgbase, 0); stageB(stgbase, Wrk, 512, 0);
    for (int kt = 0; kt < 16; kt++) {
        short* cur = stgbase + (kt & 1) * 18432;
        short* nxt = stgbase + ((kt & 1) ^ 1) * 18432;
        if (kt + 1 < 16) {
            stageA(nxt, (kt + 1) * 32); stageB(nxt, Wrk, 512, (kt + 1) * 32);
            if (wave < 4) asm volatile("s_waitcnt vmcnt(3) lgkmcnt(0)\ns_barrier" ::: "memory");
            else          asm volatile("s_waitcnt vmcnt(2) lgkmcnt(0)\ns_barrier" ::: "memory");
        } else
            asm volatile("s_waitcnt vmcnt(0) lgkmcnt(0)\ns_barrier" ::: "memory");
        kstep(cur, 0, 0);
        asm volatile("s_waitcnt lgkmcnt(0)\ns_barrier" ::: "memory");
    }
    epi_to_gtile(brk, E1);
    __syncthreads();

    // ================= G2a: g_tile(=G1) @ Wrik[k<512] =================
    clr();
    stageB(stgbase, Wrik, 1024, 0);
    for (int kt = 0; kt < 16; kt++) {
        short* cur = stgbase + (kt & 1) * 18432;
        short* nxt = stgbase + ((kt & 1) ^ 1) * 18432;
        if (kt + 1 < 16) {
            stageB(nxt, Wrik, 1024, (kt + 1) * 32);
            asm volatile("s_waitcnt vmcnt(2) lgkmcnt(0)\ns_barrier" ::: "memory");
        } else
            asm volatile("s_waitcnt vmcnt(0) lgkmcnt(0)\ns_barrier" ::: "memory");
        kstep(cur, 1, kt * 4);
        asm volatile("s_waitcnt lgkmcnt(0)\ns_barrier" ::: "memory");
    }
    // ================= G2b: kbf @ Wrik[k>=512] =================
    stageA(stgbase, 0); stageB(stgbase, Wrik, 1024, 512);
    for (int kt = 0; kt < 16; kt++) {
        short* cur = stgbase + (kt & 1) * 18432;
        short* nxt = stgbase + ((kt & 1) ^ 1) * 18432;
        if (kt + 1 < 16) {
            stageA(nxt, (kt + 1) * 32); stageB(nxt, Wrik, 1024, 512 + (kt + 1) * 32);
            if (wave < 4) asm volatile("s_waitcnt vmcnt(3) lgkmcnt(0)\ns_barrier" ::: "memory");
            else          asm volatile("s_waitcnt vmcnt(2) lgkmcnt(0)\ns_barrier" ::: "memory");
        } else
            asm volatile("s_waitcnt vmcnt(0) lgkmcnt(0)\ns_barrier" ::: "memory");
        kstep(cur, 0, 0);
        asm volatile("s_waitcnt lgkmcnt(0)\ns_barrier" ::: "memory");
    }
    epi_to_gtile(brik, E2);
    __syncthreads();

    // ================= G3: g_tile(=G2) @ Wrci =================
    clr();
    stageB(stgbase, Wrci, 512, 0);
    for (int kt = 0; kt < 16; kt++) {
        short* cur = stgbase + (kt & 1) * 18432;
        short* nxt = stgbase + ((kt & 1) ^ 1) * 18432;
        if (kt + 1 < 16) {
            stageB(nxt, Wrci, 512, (kt + 1) * 32);
            asm volatile("s_waitcnt vmcnt(2) lgkmcnt(0)\ns_barrier" ::: "memory");
        } else
            asm volatile("s_waitcnt vmcnt(0) lgkmcnt(0)\ns_barrier" ::: "memory");
        kstep(cur, 1, kt * 4);
        asm volatile("s_waitcnt lgkmcnt(0)\ns_barrier" ::: "memory");
    }
    // final epilogue: +brci, linear bf16 into g_tile, then coalesced copy out
    #pragma unroll
    for (int nt = 0; nt < 4; nt++) {
        int n = wc * 64 + nt * 16 + lrow;
        float bv = brci[n];
        #pragma unroll
        for (int t = 0; t < 2; t++)
            #pragma unroll
            for (int r = 0; r < 4; r++) {
                int row = wr * 32 + t * 16 + quad * 4 + r;
                g_tile[row * 512 + n] = (short)f2b(acc[t][nt][r] + bv);
            }
    }
    __syncthreads();
    #pragma unroll
    for (int p = 0; p < 4; p++) {
        int idx = p * 1024 + tid;                // 16B units, 4096 total
        short8 v = *(const short8*)&g_tile[idx * 8];
        *(short8*)&rai[(size_t)bm0 * 512 + (size_t)idx * 8] = v;
    }
}

// ---------------------------------------------------------------- control attention
__global__ __launch_bounds__(256) void control_attn(
    const float* __restrict__ cqi, const float* __restrict__ cws,
    const float* __restrict__ Wcai, const float* __restrict__ bcai,
    float* __restrict__ ci_f32, float* __restrict__ ci_out)
{
    int b = blockIdx.x, tid = threadIdx.x;
    __shared__ float tW[512];
    __shared__ float p[128];
    __shared__ float inv_l;
    for (int d = tid; d < 512; d += 256)
        tW[d] = cqi[(size_t)b * 512 + d] * Wcai[d];
    __syncthreads();
    int wave = tid >> 6, lane = tid & 63;
    const float* cwsb = cws + (size_t)b * 128 * 512;
    for (int s = wave; s < 128; s += 4) {
        const float* row = cwsb + (size_t)s * 512 + lane * 8;
        float acc = 0.f;
        #pragma unroll
        for (int j = 0; j < 8; j++) acc += tW[lane * 8 + j] * row[j];
        acc = wave_reduce_sum(acc);
        if (lane == 0) p[s] = acc + bcai[0];
    }
    __syncthreads();
    if (tid == 0) {
        float m = -1e30f;
        for (int s = 0; s < 128; s++) m = fmaxf(m, p[s]);
        float l = 0.f;
        for (int s = 0; s < 128; s++) { float e = __expf(p[s] - m); p[s] = e; l += e; }
        inv_l = 1.f / l;
    }
    __syncthreads();
    float inv = inv_l;
    for (int d = tid; d < 512; d += 256) {
        float acc = 0.f;
        for (int s = 0; s < 128; s++) acc += p[s] * cwsb[(size_t)s * 512 + d];
        acc *= inv;
        ci_f32[(size_t)b * 512 + d] = acc;
        ci_out[(size_t)b * 512 + d] = acc;
    }
}

// ---------------------------------------------------------------- read reduce
__global__ __launch_bounds__(256) void read_reduce(
    const u16* __restrict__ rai, const u16* __restrict__ Kb, u16* __restrict__ ri)
{
    int b = blockIdx.x >> 1;
    int d = ((blockIdx.x & 1) << 8) + threadIdx.x;
    const u16* rb = rai + (size_t)b * 196 * 512 + d;
    const u16* kb = Kb + (size_t)b * 196 * 512 + d;
    float m1[14], il1[14];
    #pragma unroll
    for (int w = 0; w < 14; w++) {
        float m = -1e30f, s = 0.f;
        #pragma unroll
        for (int h = 0; h < 14; h++) {
            float v = b2f(rb[(size_t)(h * 14 + w) * 512]);
            float nm = fmaxf(m, v);
            s = s * __expf(m - nm) + __expf(v - nm);
            m = nm;
        }
        m1[w] = m; il1[w] = 1.f / s;
    }
    float acc = 0.f;
    #pragma unroll
    for (int h = 0; h < 14; h++) {
        float pv[14], ss = 0.f;
        #pragma unroll
        for (int w = 0; w < 14; w++) {
            float pr = __expf(b2f(rb[(size_t)(h * 14 + w) * 512]) - m1[w]) * il1[w];
            float e = __expf(pr);
            pv[w] = e; ss += e;
        }
        float il2 = 1.f / ss;
        #pragma unroll
        for (int w = 0; w < 14; w++)
            acc += pv[w] * il2 * b2f(kb[(size_t)(h * 14 + w) * 512]);
    }
    ri[(size_t)b * 512 + d] = f2b(acc);
}

// ---------------------------------------------------------------- write attention + gate
__global__ __launch_bounds__(256) void write_attn(
    const float* __restrict__ ci_f32, const float* __restrict__ C_past,
    const float* __restrict__ M_past,
    const float* __restrict__ Wwcc, const float* __restrict__ bwcc,
    const float* __restrict__ Wwci, const float* __restrict__ bwci,
    u16* __restrict__ mi_sa, float* __restrict__ gate)
{
    int b = blockIdx.x, tid = threadIdx.x;
    __shared__ float c[512];
    __shared__ float pt[12];
    __shared__ float red[256];
    for (int d = tid; d < 512; d += 256) c[d] = ci_f32[(size_t)b * 512 + d];
    __syncthreads();
    float g = 0.f;
    for (int d = tid; d < 512; d += 256) g += c[d] * Wwci[d];
    red[tid] = g;
    __syncthreads();
    for (int s = 128; s > 0; s >>= 1) {
        if (tid < s) red[tid] += red[tid + s];
        __syncthreads();
    }
    int wave = tid >> 6, lane = tid & 63;
    const float* cp = C_past + (size_t)b * 12 * 512;
    for (int t = wave; t < 12; t += 4) {
        float acc = 0.f;
        #pragma unroll
        for (int j = 0; j < 8; j++) {
            int d = lane * 8 + j;
            acc += c[d] * Wwcc[d] * cp[(size_t)t * 512 + d];
        }
        acc = wave_reduce_sum(acc);
        if (lane == 0) pt[t] = acc + bwcc[0];
    }
    __syncthreads();
    if (tid == 0) {
        float m = -1e30f;
        for (int t = 0; t < 12; t++) m = fmaxf(m, pt[t]);
        float l = 0.f;
        for (int t = 0; t < 12; t++) { float e = __expf(pt[t] - m); pt[t] = e; l += e; }
        float invl = 1.f / l;
        for (int t = 0; t < 12; t++) pt[t] *= invl;
        gate[b] = 1.f / (1.f + __expf(-(red[0] + bwci[0])));
    }
    __syncthreads();
    const float* mp = M_past + (size_t)b * 12 * 512;
    for (int d = tid; d < 512; d += 256) {
        float acc = 0.f;
        #pragma unroll
        for (int t = 0; t < 12; t++) acc += pt[t] * mp[(size_t)t * 512 + d];
        mi_sa[(size_t)b * 512 + d] = f2b(acc);
    }
}

// ---------------------------------------------------------------- launch
extern "C" void kernel_launch(void* const* d_in, const int* in_sizes, int n_in,
                              void* d_out, int out_size, void* d_ws, size_t ws_size,
                              hipStream_t stream) {
    (void)in_sizes; (void)n_in; (void)out_size;
    const int B = 256, D = 512, HW = 196;

    const float* ci_1   = (const float*)d_in[0];
    const float* mi_1   = (const float*)d_in[1];
    const float* q      = (const float*)d_in[2];
    const float* cws    = (const float*)d_in[3];
    const float* Kin    = (const float*)d_in[4];
    const float* C_past = (const float*)d_in[5];
    const float* M_past = (const float*)d_in[6];
    const float* W_cq   = (const float*)d_in[7];
    const float* b_cq   = (const float*)d_in[8];
    const float* W_cqi  = (const float*)d_in[9];
    const float* b_cqi  = (const float*)d_in[10];
    const float* W_cai  = (const float*)d_in[11];
    const float* b_cai  = (const float*)d_in[12];
    const float* W_rm   = (const float*)d_in[13];
    const float* b_rm   = (const float*)d_in[14];
    const float* W_rk   = (const float*)d_in[15];
    const float* b_rk   = (const float*)d_in[16];
    const float* W_rik  = (const float*)d_in[17];
    const float* b_rik  = (const float*)d_in[18];
    const float* W_rci  = (const float*)d_in[19];
    const float* b_rci  = (const float*)d_in[20];
    const float* W_wrm  = (const float*)d_in[21];
    const float* b_wrm  = (const float*)d_in[22];
    const float* W_wcc  = (const float*)d_in[23];
    const float* b_wcc  = (const float*)d_in[24];
    const float* W_wsa  = (const float*)d_in[25];
    const float* b_wsa  = (const float*)d_in[26];
    const float* W_winfo= (const float*)d_in[27];
    const float* b_winfo= (const float*)d_in[28];
    const float* W_wci  = (const float*)d_in[29];
    const float* b_wci  = (const float*)d_in[30];

    float* out_ci = (float*)d_out;
    float* out_mi = (float*)d_out + (size_t)B * D;

    char* ws = (char*)d_ws;
    size_t off = 0;
    auto alloc = [&](size_t bytes) -> void* {
        void* p = ws + off; off += (bytes + 255) & ~(size_t)255; return p;
    };
    u16* wt_cq    = (u16*)alloc((size_t)D * D * 2);
    u16* wt_cqi   = (u16*)alloc((size_t)D * 2 * D * 2);
    u16* wt_rm    = (u16*)alloc((size_t)D * D * 2);
    u16* wt_rk    = (u16*)alloc((size_t)D * D * 2);
    u16* wt_rik   = (u16*)alloc((size_t)D * 2 * D * 2);
    u16* wt_rci   = (u16*)alloc((size_t)D * D * 2);
    u16* wt_wrm   = (u16*)alloc((size_t)D * 2 * D * 2);
    u16* wt_wsi   = (u16*)alloc((size_t)D * 2 * D * 2);
    u16* qb       = (u16*)alloc((size_t)B * D * 2);
    u16* cib      = (u16*)alloc((size_t)B * D * 2);
    u16* mib      = (u16*)alloc((size_t)B * D * 2);
    u16* qi_buf   = (u16*)alloc((size_t)B * D * 2);
    float* cqi_f32= (float*)alloc((size_t)B * D * 4);
    float* rm_f32 = (float*)alloc((size_t)B * D * 4);
    float* ci_f32 = (float*)alloc((size_t)B * D * 4);
    u16* ri_buf   = (u16*)alloc((size_t)B * D * 2);
    u16* misa_buf = (u16*)alloc((size_t)B * D * 2);
    u16* minfo_buf= (u16*)alloc((size_t)B * D * 2);
    float* gate_b = (float*)alloc((size_t)B * 4);

    int chunk_b = 256;
    while (chunk_b > 32) {
        size_t need = off + 2 * (((size_t)chunk_b * HW * D * 2 + 255) & ~(size_t)255);
        if (need <= ws_size) break;
        chunk_b >>= 1;
    }
    u16* kbf  = (u16*)alloc((size_t)chunk_b * HW * D * 2);
    u16* big1 = (u16*)alloc((size_t)chunk_b * HW * D * 2);

    // batched weight transposes (one launch)
    TBatch tb;
    const float* tin[9] = {W_cq, W_cqi, W_rm, W_rk, W_rik, W_rci, W_wrm, W_wsa, W_winfo};
    u16* tout[9] = {wt_cq, wt_cqi, wt_rm, wt_rk, wt_rik, wt_rci, wt_wrm, wt_wsi, wt_wsi};
    int tK[9]  = {512, 1024, 512, 512, 1024, 512, 1024, 512, 512};
    int tos[9] = {512, 1024, 512, 512, 1024, 512, 1024, 1024, 1024};
    int tko[9] = {0, 0, 0, 0, 0, 0, 0, 0, 512};
    int tbase = 0;
    for (int i = 0; i < 9; i++) {
        tb.in[i] = tin[i]; tb.out[i] = tout[i]; tb.K[i] = tK[i];
        tb.ostride[i] = tos[i]; tb.koff[i] = tko[i]; tb.tbase[i] = tbase;
        tbase += (tK[i] / 32) * 16;
    }
    transpose_batch<<<tbase, dim3(32, 8), 0, stream>>>(tb);

    conv3_f32_bf16<<<384, 256, 0, stream>>>(q, ci_1, mi_1, qb, cib, mib);

    dim3 gsmall(D / 64, B / 64); // (8, 4) = 32 blocks

    gemm_mfma<2,2><<<gsmall, 256, 0, stream>>>(qb, nullptr, B, D, 0, D, wt_cq, b_cq, nullptr,
                                               0, nullptr, 1, nullptr, nullptr, qi_buf, 0);
    gemm_mfma<2,2><<<gsmall, 256, 0, stream>>>(cib, qi_buf, B, D, D, D, wt_cqi, b_cqi, nullptr,
                                               0, nullptr, 1, nullptr, nullptr, cqi_f32, 1);
    control_attn<<<B, 256, 0, stream>>>(cqi_f32, cws, W_cai, b_cai, ci_f32, out_ci);
    gemm_mfma<2,2><<<gsmall, 256, 0, stream>>>(mib, nullptr, B, D, 0, D, wt_rm, b_rm, nullptr,
                                               0, nullptr, 1, nullptr, nullptr, rm_f32, 1);

    for (int c = 0; c < B; c += chunk_b) {
        int mrows = chunk_b * HW;
        const float* Kc = Kin + (size_t)c * HW * D;
        conv_f32_bf16<<<(mrows * D) / 1024, 256, 0, stream>>>(Kc, kbf, mrows * D);
        fused_read<<<mrows / 64, 1024, 0, stream>>>(
            kbf, mrows,
            wt_rk,  b_rk,  rm_f32 + (size_t)c * D,
            wt_rik, b_rik, ci_f32 + (size_t)c * D,
            wt_rci, b_rci,
            big1);
        read_reduce<<<chunk_b * 2, 256, 0, stream>>>(big1, kbf, ri_buf + (size_t)c * D);
    }

    gemm_mfma<2,2><<<gsmall, 256, 0, stream>>>(ri_buf, mib, B, D, D, D, wt_wrm, b_wrm, nullptr,
                                               0, nullptr, 1, nullptr, nullptr, minfo_buf, 0);
    write_attn<<<B, 256, 0, stream>>>(ci_f32, C_past, M_past, W_wcc, b_wcc, W_wci, b_wci,
                                      misa_buf, gate_b);
    gemm_mfma<2,2><<<gsmall, 256, 0, stream>>>(misa_buf, minfo_buf, B, D, D, D, wt_wsi,
                                               b_wsa, b_winfo, 2, nullptr, 1, gate_b, mi_1,
                                               out_mi, 1);
}